// Round 5
// baseline (221.070 us; speedup 1.0000x reference)
//
#include <hip/hip_runtime.h>

// SSIM loss: Xt, Yt are [B=16, C=1, T=20, H=256, W=256] fp32.
// Frame f = b*20 + t contiguous 65536 floats. dr[t] = max over Yt[:,:,t].
// S per 7x7 valid window (250x250/frame); out = 1 - mean(S).

#define HH 256
#define WW 256
#define OUTW 250
#define NT 20
#define NB 16
#define NFRAMES (NT * NB)        // 320
#define STRIPS 25
#define RPS 10                   // output rows per strip (25*10 = 250)
#define NWAVES (NFRAMES * STRIPS) // 8000
#define WPB 4                    // waves per block
#define NBLK2 (NWAVES / WPB)     // 2000

// Compiler-only memory fence: pins program order of LDS ops (HW executes
// same-wave DS ops in order; we only need to stop compiler reordering).
#define LDS_FENCE() asm volatile("" ::: "memory")

__device__ __forceinline__ float wave_sum(float v) {
#pragma unroll
    for (int off = 32; off > 0; off >>= 1) v += __shfl_down(v, off, 64);
    return v;
}
__device__ __forceinline__ float wave_max(float v) {
#pragma unroll
    for (int off = 32; off > 0; off >>= 1) v = fmaxf(v, __shfl_down(v, off, 64));
    return v;
}

// ---------------- Pass 1: per-t max over Yt (quarter-frame blocks) ----------
__global__ __launch_bounds__(256) void dr_max_kernel(const float* __restrict__ Y,
                                                     unsigned* __restrict__ dr_bits) {
    int t = blockIdx.x;          // 0..19
    int bq = blockIdx.y;         // 0..63 : b = bq>>2, quarter = bq&3
    const float4* p = (const float4*)(Y + (size_t)((bq >> 2) * NT + t) * (HH * WW))
                      + (bq & 3) * 4096;
    float m = 0.f;               // inputs uniform [0,1) => non-negative
#pragma unroll 4
    for (int k = 0; k < 16; ++k) {
        float4 v = p[k * 256 + threadIdx.x];
        m = fmaxf(m, fmaxf(fmaxf(v.x, v.y), fmaxf(v.z, v.w)));
    }
    m = wave_max(m);
    __shared__ float smax[4];
    int lane = threadIdx.x & 63, w = threadIdx.x >> 6;
    if (lane == 0) smax[w] = m;
    __syncthreads();
    if (threadIdx.x == 0) {
        float mm = fmaxf(fmaxf(smax[0], smax[1]), fmaxf(smax[2], smax[3]));
        atomicMax(dr_bits + t, __float_as_uint(mm));  // non-neg: uint cmp == float cmp
    }
}

// ---------------- Pass 2: SSIM, 4 independent waves/block ------------------
// Each wave owns one (frame, strip); 64 lanes x 4 cols = 256 cols.
// Vertical 7-row running sums in registers; horizontal 7-tap via wave-private
// LDS halo. No s_barrier: same-wave DS ops are HW-ordered; LDS_FENCE() pins
// the compiler's program order (R3 failed because halo reads were hoisted).
// STRIPS=25 -> 8000 waves (~28 resident/CU) to cover LDS+VALU latency (R4 was
// wave-starved at 12.5/CU: VALU 44%, HBM 36%, LDS ~37% all simultaneously).

// S scaled by 49^2 top & bottom (cancels): c1=2401*C1, c2=2401*C2.
__device__ __forceinline__ float ssim_px(float hx, float hy, float hxx, float hyy,
                                         float hxy, float c1, float c2) {
    const float cov = 49.0f / 48.0f;
    float hx2 = hx * hx, hy2 = hy * hy, hxy1 = hx * hy;
    float A1 = __builtin_fmaf(2.f, hxy1, c1);
    float B1 = hx2 + hy2 + c1;
    float t1 = __builtin_fmaf(49.f, hxx, -hx2);
    float t2 = __builtin_fmaf(49.f, hyy, -hy2);
    float t3 = __builtin_fmaf(49.f, hxy, -hxy1);
    float A2 = __builtin_fmaf(2.f * cov, t3, c2);
    float B2 = __builtin_fmaf(cov, t1 + t2, c2);
    return (A1 * A2) * __builtin_amdgcn_rcpf(B1 * B2);
}

// 7-tap horizontal sums for 4 consecutive output cols: own colsums s (cols c..c+3)
// + halo cols c+4..c+9 from LDS.
__device__ __forceinline__ float4 taps7(float4 s, const float* halo /*&ls[c0+4]*/) {
    float4 ha = *(const float4*)halo;        // cols c+4..c+7
    float2 hb = *(const float2*)(halo + 4);  // cols c+8..c+9
    float o0 = s.x + s.y + s.z + s.w + ha.x + ha.y + ha.z;  // cols c..c+6
    float o1 = o0 - s.x + ha.w;
    float o2 = o1 - s.y + hb.x;
    float o3 = o2 - s.z + hb.y;
    return make_float4(o0, o1, o2, o3);
}

#define LSW (WW + 16)  // 272 floats per moment row

__global__ __launch_bounds__(256) void ssim_kernel(const float* __restrict__ X,
                                                   const float* __restrict__ Y,
                                                   const float* __restrict__ dr_arr,
                                                   float* __restrict__ partials) {
    __shared__ __align__(16) float ls_all[WPB][5][LSW];  // 21760 B -> 7 blocks/CU
    int w = threadIdx.x >> 6;
    int l = threadIdx.x & 63;
    int wid = blockIdx.x * WPB + w;
    int frame = wid / STRIPS;   // 0..319
    int strip = wid % STRIPS;
    int t = frame % NT;
    const float4* x4 = (const float4*)(X + (size_t)frame * (HH * WW));
    const float4* y4 = (const float4*)(Y + (size_t)frame * (HH * WW));
    float (*ls)[LSW] = ls_all[w];
    int c0 = 4 * l;

    float dr = dr_arr[t];
    float c1 = 2401.f * (0.01f * dr) * (0.01f * dr);
    float c2 = 2401.f * (0.03f * dr) * (0.03f * dr);

    int r0 = strip * RPS;

    // vertical running column-sums (4 cols/lane) over rows r0..r0+6
    float4 sx = make_float4(0, 0, 0, 0), sy = sx, sxx = sx, syy = sx, sxy = sx;
#pragma unroll
    for (int dy = 0; dy < 7; ++dy) {
        float4 xv = x4[(r0 + dy) * 64 + l];
        float4 yv = y4[(r0 + dy) * 64 + l];
        sx.x += xv.x; sx.y += xv.y; sx.z += xv.z; sx.w += xv.w;
        sy.x += yv.x; sy.y += yv.y; sy.z += yv.z; sy.w += yv.w;
        sxx.x += xv.x * xv.x; sxx.y += xv.y * xv.y; sxx.z += xv.z * xv.z; sxx.w += xv.w * xv.w;
        syy.x += yv.x * yv.x; syy.y += yv.y * yv.y; syy.z += yv.z * yv.z; syy.w += yv.w * yv.w;
        sxy.x += xv.x * yv.x; sxy.y += xv.y * yv.y; sxy.z += xv.z * yv.z; sxy.w += xv.w * yv.w;
    }

    float acc = 0.f;
    for (int r = r0; r < r0 + RPS; ++r) {
        *(float4*)&ls[0][c0] = sx;
        *(float4*)&ls[1][c0] = sy;
        *(float4*)&ls[2][c0] = sxx;
        *(float4*)&ls[3][c0] = syy;
        *(float4*)&ls[4][c0] = sxy;

        bool more = (r + 1 < r0 + RPS);
        float4 xo, yo, xn, yn;
        if (more) {  // issue slide loads early; latency hidden under tap/SSIM math
            xo = x4[r * 64 + l];       yo = y4[r * 64 + l];
            xn = x4[(r + 7) * 64 + l]; yn = y4[(r + 7) * 64 + l];
        }

        LDS_FENCE();  // writes above must stay above the halo reads below

        float4 hx  = taps7(sx,  &ls[0][c0 + 4]);
        float4 hy  = taps7(sy,  &ls[1][c0 + 4]);
        float4 hxx = taps7(sxx, &ls[2][c0 + 4]);
        float4 hyy = taps7(syy, &ls[3][c0 + 4]);
        float4 hxy = taps7(sxy, &ls[4][c0 + 4]);

        LDS_FENCE();  // reads above must stay above next iteration's writes

        // lanes 0..61: all 4 valid; lane 62 (c0=248): 2 valid; lane 63: none
        if (c0 + 0 < OUTW) acc += ssim_px(hx.x, hy.x, hxx.x, hyy.x, hxy.x, c1, c2);
        if (c0 + 1 < OUTW) acc += ssim_px(hx.y, hy.y, hxx.y, hyy.y, hxy.y, c1, c2);
        if (c0 + 2 < OUTW) acc += ssim_px(hx.z, hy.z, hxx.z, hyy.z, hxy.z, c1, c2);
        if (c0 + 3 < OUTW) acc += ssim_px(hx.w, hy.w, hxx.w, hyy.w, hxy.w, c1, c2);

        if (more) {  // slide window: add row r+7, drop row r
            sx.x += xn.x - xo.x; sx.y += xn.y - xo.y; sx.z += xn.z - xo.z; sx.w += xn.w - xo.w;
            sy.x += yn.x - yo.x; sy.y += yn.y - yo.y; sy.z += yn.z - yo.z; sy.w += yn.w - yo.w;
            sxx.x += xn.x * xn.x - xo.x * xo.x; sxx.y += xn.y * xn.y - xo.y * xo.y;
            sxx.z += xn.z * xn.z - xo.z * xo.z; sxx.w += xn.w * xn.w - xo.w * xo.w;
            syy.x += yn.x * yn.x - yo.x * yo.x; syy.y += yn.y * yn.y - yo.y * yo.y;
            syy.z += yn.z * yn.z - yo.z * yo.z; syy.w += yn.w * yn.w - yo.w * yo.w;
            sxy.x += xn.x * yn.x - xo.x * yo.x; sxy.y += xn.y * yn.y - xo.y * yo.y;
            sxy.z += xn.z * yn.z - xo.z * yo.z; sxy.w += xn.w * yn.w - xo.w * yo.w;
        }
    }

    acc = wave_sum(acc);
    if (l == 0) partials[wid] = acc;
}

// ---------------- Pass 3: final reduce ----------------
__global__ __launch_bounds__(256) void final_kernel(const float* __restrict__ partials,
                                                    float* __restrict__ out) {
    float s = 0.f;
    for (int i = threadIdx.x; i < NWAVES; i += 256) s += partials[i];
    s = wave_sum(s);
    __shared__ float ssum[4];
    int lane = threadIdx.x & 63, w = threadIdx.x >> 6;
    if (lane == 0) ssum[w] = s;
    __syncthreads();
    if (threadIdx.x == 0) {
        float total = ssum[0] + ssum[1] + ssum[2] + ssum[3];
        const double denom = (double)NFRAMES * OUTW * OUTW;
        out[0] = (float)(1.0 - (double)total / denom);
    }
}

extern "C" void kernel_launch(void* const* d_in, const int* in_sizes, int n_in,
                              void* d_out, int out_size, void* d_ws, size_t ws_size,
                              hipStream_t stream) {
    const float* X = (const float*)d_in[0];
    const float* Y = (const float*)d_in[1];

    float* ws = (float*)d_ws;
    unsigned* dr_bits = (unsigned*)ws;   // [0..20)
    float* partials   = ws + 32;         // [32..32+8000)

    hipMemsetAsync(d_ws, 0, NT * sizeof(float), stream);

    dim3 g1(NT, NB * 4);
    hipLaunchKernelGGL(dr_max_kernel, g1, dim3(256), 0, stream, Y, dr_bits);
    hipLaunchKernelGGL(ssim_kernel, dim3(NBLK2), dim3(256), 0, stream,
                       X, Y, (const float*)ws, partials);
    hipLaunchKernelGGL(final_kernel, dim3(1), dim3(256), 0, stream,
                       partials, (float*)d_out);
}

// Round 6
// 215.816 us; speedup vs baseline: 1.0243x; 1.0243x over previous
//
#include <hip/hip_runtime.h>

// SSIM loss: Xt, Yt are [B=16, C=1, T=20, H=256, W=256] fp32.
// Frame f = b*20 + t contiguous 65536 floats. dr[t] = max over Yt[:,:,t].
// S per 7x7 valid window (250x250/frame); out = 1 - mean(S).

#define HH 256
#define WW 256
#define OUTW 250
#define NT 20
#define NB 16
#define NFRAMES (NT * NB)        // 320
#define STRIPS 25
#define RPS 10                   // output rows per strip (25*10 = 250), even
#define NWAVES (NFRAMES * STRIPS) // 8000
#define WPB 4                    // waves per block
#define NBLK2 (NWAVES / WPB)     // 2000

// Compiler-only memory fence: pins program order of LDS ops (HW executes
// same-wave DS ops in order; we only need to stop compiler reordering).
#define LDS_FENCE() asm volatile("" ::: "memory")

__device__ __forceinline__ float wave_sum(float v) {
#pragma unroll
    for (int off = 32; off > 0; off >>= 1) v += __shfl_down(v, off, 64);
    return v;
}
__device__ __forceinline__ float wave_max(float v) {
#pragma unroll
    for (int off = 32; off > 0; off >>= 1) v = fmaxf(v, __shfl_down(v, off, 64));
    return v;
}

// ---------------- Pass 1: per-t max over Yt (quarter-frame blocks) ----------
__global__ __launch_bounds__(256) void dr_max_kernel(const float* __restrict__ Y,
                                                     unsigned* __restrict__ dr_bits) {
    int t = blockIdx.x;          // 0..19
    int bq = blockIdx.y;         // 0..63 : b = bq>>2, quarter = bq&3
    const float4* p = (const float4*)(Y + (size_t)((bq >> 2) * NT + t) * (HH * WW))
                      + (bq & 3) * 4096;
    float m = 0.f;               // inputs uniform [0,1) => non-negative
#pragma unroll 4
    for (int k = 0; k < 16; ++k) {
        float4 v = p[k * 256 + threadIdx.x];
        m = fmaxf(m, fmaxf(fmaxf(v.x, v.y), fmaxf(v.z, v.w)));
    }
    m = wave_max(m);
    __shared__ float smax[4];
    int lane = threadIdx.x & 63, w = threadIdx.x >> 6;
    if (lane == 0) smax[w] = m;
    __syncthreads();
    if (threadIdx.x == 0) {
        float mm = fmaxf(fmaxf(smax[0], smax[1]), fmaxf(smax[2], smax[3]));
        atomicMax(dr_bits + t, __float_as_uint(mm));  // non-neg: uint cmp == float cmp
    }
}

// ---------------- Pass 2: SSIM, 4 independent waves/block ------------------
// Each wave owns one (frame, strip); 64 lanes x 4 cols = 256 cols.
// Vertical 7-row running sums in registers; horizontal 7-tap via wave-private
// LDS halo. No s_barrier: same-wave DS ops are HW-ordered; LDS_FENCE pins the
// compiler's program order. R6: double-buffered LDS + 2 rows/iteration +
// __launch_bounds__(256,4) (VGPR<=128) so the compiler can pipeline rows
// instead of serializing into 52 VGPRs (R2/R4/R5 all pinned at ~62us).

// S scaled by 49^2 top & bottom (cancels): c1=2401*C1, c2=2401*C2.
__device__ __forceinline__ float ssim_px(float hx, float hy, float hxx, float hyy,
                                         float hxy, float c1, float c2) {
    const float cov = 49.0f / 48.0f;
    float hx2 = hx * hx, hy2 = hy * hy, hxy1 = hx * hy;
    float A1 = __builtin_fmaf(2.f, hxy1, c1);
    float B1 = hx2 + hy2 + c1;
    float t1 = __builtin_fmaf(49.f, hxx, -hx2);
    float t2 = __builtin_fmaf(49.f, hyy, -hy2);
    float t3 = __builtin_fmaf(49.f, hxy, -hxy1);
    float A2 = __builtin_fmaf(2.f * cov, t3, c2);
    float B2 = __builtin_fmaf(cov, t1 + t2, c2);
    return (A1 * A2) * __builtin_amdgcn_rcpf(B1 * B2);
}

// 7-tap horizontal sums for 4 consecutive output cols: own colsums s (cols c..c+3)
// + halo cols c+4..c+9 from LDS.
__device__ __forceinline__ float4 taps7(float4 s, const float* halo /*&ls[c0+4]*/) {
    float4 ha = *(const float4*)halo;        // cols c+4..c+7
    float2 hb = *(const float2*)(halo + 4);  // cols c+8..c+9
    float o0 = s.x + s.y + s.z + s.w + ha.x + ha.y + ha.z;  // cols c..c+6
    float o1 = o0 - s.x + ha.w;
    float o2 = o1 - s.y + hb.x;
    float o3 = o2 - s.z + hb.y;
    return make_float4(o0, o1, o2, o3);
}

__device__ __forceinline__ void slide5(float4& sx, float4& sy, float4& sxx,
                                       float4& syy, float4& sxy,
                                       float4 xo, float4 yo, float4 xn, float4 yn) {
    sx.x += xn.x - xo.x; sx.y += xn.y - xo.y; sx.z += xn.z - xo.z; sx.w += xn.w - xo.w;
    sy.x += yn.x - yo.x; sy.y += yn.y - yo.y; sy.z += yn.z - yo.z; sy.w += yn.w - yo.w;
    sxx.x += xn.x * xn.x - xo.x * xo.x; sxx.y += xn.y * xn.y - xo.y * xo.y;
    sxx.z += xn.z * xn.z - xo.z * xo.z; sxx.w += xn.w * xn.w - xo.w * xo.w;
    syy.x += yn.x * yn.x - yo.x * yo.x; syy.y += yn.y * yn.y - yo.y * yo.y;
    syy.z += yn.z * yn.z - yo.z * yo.z; syy.w += yn.w * yn.w - yo.w * yo.w;
    sxy.x += xn.x * yn.x - xo.x * yo.x; sxy.y += xn.y * yn.y - xo.y * yo.y;
    sxy.z += xn.z * yn.z - xo.z * yo.z; sxy.w += xn.w * yn.w - xo.w * yo.w;
}

#define LSW (WW + 16)  // 272 floats per moment row

__global__ __launch_bounds__(256, 4) void ssim_kernel(const float* __restrict__ X,
                                                      const float* __restrict__ Y,
                                                      const float* __restrict__ dr_arr,
                                                      float* __restrict__ partials) {
    __shared__ __align__(16) float ls_all[WPB][2][5][LSW];  // 43520 B -> 3 blocks/CU
    int w = threadIdx.x >> 6;
    int l = threadIdx.x & 63;
    int wid = blockIdx.x * WPB + w;
    int frame = wid / STRIPS;   // 0..319
    int strip = wid % STRIPS;
    int t = frame % NT;
    const float4* x4 = (const float4*)(X + (size_t)frame * (HH * WW));
    const float4* y4 = (const float4*)(Y + (size_t)frame * (HH * WW));
    float (*ls0)[LSW] = ls_all[w][0];
    float (*ls1)[LSW] = ls_all[w][1];
    int c0 = 4 * l;

    float dr = dr_arr[t];
    float c1 = 2401.f * (0.01f * dr) * (0.01f * dr);
    float c2 = 2401.f * (0.03f * dr) * (0.03f * dr);

    int r0 = strip * RPS;

    // vertical running column-sums (4 cols/lane) over rows r0..r0+6
    float4 sx = make_float4(0, 0, 0, 0), sy = sx, sxx = sx, syy = sx, sxy = sx;
#pragma unroll
    for (int dy = 0; dy < 7; ++dy) {
        float4 xv = x4[(r0 + dy) * 64 + l];
        float4 yv = y4[(r0 + dy) * 64 + l];
        sx.x += xv.x; sx.y += xv.y; sx.z += xv.z; sx.w += xv.w;
        sy.x += yv.x; sy.y += yv.y; sy.z += yv.z; sy.w += yv.w;
        sxx.x += xv.x * xv.x; sxx.y += xv.y * xv.y; sxx.z += xv.z * xv.z; sxx.w += xv.w * xv.w;
        syy.x += yv.x * yv.x; syy.y += yv.y * yv.y; syy.z += yv.z * yv.z; syy.w += yv.w * yv.w;
        sxy.x += xv.x * yv.x; sxy.y += xv.y * yv.y; sxy.z += xv.z * yv.z; sxy.w += xv.w * yv.w;
    }

    float acc = 0.f;
    for (int it = 0; it < RPS / 2; ++it) {
        int r = r0 + 2 * it;       // rows r (buf0) and r+1 (buf1) this iteration
        bool lastit = (it == RPS / 2 - 1);

        // issue all slide loads up front (latency hidden under LDS + math)
        float4 xa = x4[r * 64 + l],       ya = y4[r * 64 + l];        // old, slide1
        float4 xb = x4[(r + 7) * 64 + l], yb = y4[(r + 7) * 64 + l];  // new, slide1
        float4 xc, yc, xd, yd;
        if (!lastit) {
            xc = x4[(r + 1) * 64 + l]; yc = y4[(r + 1) * 64 + l];     // old, slide2
            xd = x4[(r + 8) * 64 + l]; yd = y4[(r + 8) * 64 + l];     // new, slide2
        }

        // row r -> buf0
        *(float4*)&ls0[0][c0] = sx;
        *(float4*)&ls0[1][c0] = sy;
        *(float4*)&ls0[2][c0] = sxx;
        *(float4*)&ls0[3][c0] = syy;
        *(float4*)&ls0[4][c0] = sxy;

        LDS_FENCE();  // buf0 writes before buf0 reads (also orders prev R1 vs these W0)

        float4 h0x  = taps7(sx,  &ls0[0][c0 + 4]);
        float4 h0y  = taps7(sy,  &ls0[1][c0 + 4]);
        float4 h0xx = taps7(sxx, &ls0[2][c0 + 4]);
        float4 h0yy = taps7(syy, &ls0[3][c0 + 4]);
        float4 h0xy = taps7(sxy, &ls0[4][c0 + 4]);

        // slide to row r+1 window, write buf1 (overlaps buf0 reads in HW queue)
        slide5(sx, sy, sxx, syy, sxy, xa, ya, xb, yb);

        *(float4*)&ls1[0][c0] = sx;
        *(float4*)&ls1[1][c0] = sy;
        *(float4*)&ls1[2][c0] = sxx;
        *(float4*)&ls1[3][c0] = syy;
        *(float4*)&ls1[4][c0] = sxy;

        LDS_FENCE();  // buf1 writes before buf1 reads (also orders R0 vs next W0)

        float4 h1x  = taps7(sx,  &ls1[0][c0 + 4]);
        float4 h1y  = taps7(sy,  &ls1[1][c0 + 4]);
        float4 h1xx = taps7(sxx, &ls1[2][c0 + 4]);
        float4 h1yy = taps7(syy, &ls1[3][c0 + 4]);
        float4 h1xy = taps7(sxy, &ls1[4][c0 + 4]);

        // lanes 0..61: all 4 valid; lane 62 (c0=248): 2 valid; lane 63: none
        if (c0 + 0 < OUTW) acc += ssim_px(h0x.x, h0y.x, h0xx.x, h0yy.x, h0xy.x, c1, c2)
                                + ssim_px(h1x.x, h1y.x, h1xx.x, h1yy.x, h1xy.x, c1, c2);
        if (c0 + 1 < OUTW) acc += ssim_px(h0x.y, h0y.y, h0xx.y, h0yy.y, h0xy.y, c1, c2)
                                + ssim_px(h1x.y, h1y.y, h1xx.y, h1yy.y, h1xy.y, c1, c2);
        if (c0 + 2 < OUTW) acc += ssim_px(h0x.z, h0y.z, h0xx.z, h0yy.z, h0xy.z, c1, c2)
                                + ssim_px(h1x.z, h1y.z, h1xx.z, h1yy.z, h1xy.z, c1, c2);
        if (c0 + 3 < OUTW) acc += ssim_px(h0x.w, h0y.w, h0xx.w, h0yy.w, h0xy.w, c1, c2)
                                + ssim_px(h1x.w, h1y.w, h1xx.w, h1yy.w, h1xy.w, c1, c2);

        if (!lastit)  // slide to row r+2 window for next iteration
            slide5(sx, sy, sxx, syy, sxy, xc, yc, xd, yd);
    }

    acc = wave_sum(acc);
    if (l == 0) partials[wid] = acc;
}

// ---------------- Pass 3: final reduce ----------------
__global__ __launch_bounds__(256) void final_kernel(const float* __restrict__ partials,
                                                    float* __restrict__ out) {
    float s = 0.f;
    for (int i = threadIdx.x; i < NWAVES; i += 256) s += partials[i];
    s = wave_sum(s);
    __shared__ float ssum[4];
    int lane = threadIdx.x & 63, w = threadIdx.x >> 6;
    if (lane == 0) ssum[w] = s;
    __syncthreads();
    if (threadIdx.x == 0) {
        float total = ssum[0] + ssum[1] + ssum[2] + ssum[3];
        const double denom = (double)NFRAMES * OUTW * OUTW;
        out[0] = (float)(1.0 - (double)total / denom);
    }
}

extern "C" void kernel_launch(void* const* d_in, const int* in_sizes, int n_in,
                              void* d_out, int out_size, void* d_ws, size_t ws_size,
                              hipStream_t stream) {
    const float* X = (const float*)d_in[0];
    const float* Y = (const float*)d_in[1];

    float* ws = (float*)d_ws;
    unsigned* dr_bits = (unsigned*)ws;   // [0..20)
    float* partials   = ws + 32;         // [32..32+8000)

    hipMemsetAsync(d_ws, 0, NT * sizeof(float), stream);

    dim3 g1(NT, NB * 4);
    hipLaunchKernelGGL(dr_max_kernel, g1, dim3(256), 0, stream, Y, dr_bits);
    hipLaunchKernelGGL(ssim_kernel, dim3(NBLK2), dim3(256), 0, stream,
                       X, Y, (const float*)ws, partials);
    hipLaunchKernelGGL(final_kernel, dim3(1), dim3(256), 0, stream,
                       partials, (float*)d_out);
}